// Round 3
// baseline (1503.507 us; speedup 1.0000x reference)
//
#include <hip/hip_runtime.h>
#include <math.h>

#define NB 2
#define NN 4096
#define NC 128
#define NH 4
#define HD 32
#define C2 256
#define HW 64
#define EPS 1e-5f

// ---------- helpers ----------
__device__ __forceinline__ float block_reduce_sum_128(float v, float* sbuf, int tid) {
    // butterfly within wave (all lanes end with wave sum)
    #pragma unroll
    for (int off = 32; off > 0; off >>= 1) v += __shfl_xor(v, off, 64);
    __syncthreads();                 // protect sbuf from previous use
    if ((tid & 63) == 0) sbuf[tid >> 6] = v;
    __syncthreads();
    return sbuf[0] + sbuf[1];
}

// ---------- K1: LN1 + QKV projection ----------
// grid = B*N rows, block = 128
__global__ __launch_bounds__(128) void k_ln_qkv(
    const float* __restrict__ x, const float* __restrict__ ln_w, const float* __restrict__ ln_b,
    const float* __restrict__ q_w, const float* __restrict__ kv_w,
    float* __restrict__ qo, float* __restrict__ ko, float* __restrict__ vo) {
    __shared__ float sh[NC];
    __shared__ float sred[2];
    const int row = blockIdx.x;       // b*NN + n
    const int tid = threadIdx.x;      // output feature o (0..127)

    float xv = x[(size_t)row * NC + tid];
    float mean = block_reduce_sum_128(xv, sred, tid) * (1.0f / NC);
    float d = xv - mean;
    float var = block_reduce_sum_128(d * d, sred, tid) * (1.0f / NC);
    float hv = d * rsqrtf(var + EPS) * ln_w[tid] + ln_b[tid];
    sh[tid] = hv;
    __syncthreads();

    const float4* h4 = (const float4*)sh;
    const float4* wq = (const float4*)(q_w + (size_t)tid * NC);
    const float4* wk = (const float4*)(kv_w + (size_t)tid * NC);
    const float4* wv = (const float4*)(kv_w + (size_t)(NC + tid) * NC);
    float aq = 0.f, ak = 0.f, av = 0.f;
    #pragma unroll
    for (int c = 0; c < NC / 4; ++c) {
        float4 h = h4[c];
        float4 a = wq[c];
        float4 b = wk[c];
        float4 g = wv[c];
        aq += h.x * a.x + h.y * a.y + h.z * a.z + h.w * a.w;
        ak += h.x * b.x + h.y * b.y + h.z * b.z + h.w * b.w;
        av += h.x * g.x + h.y * g.y + h.z * g.z + h.w * g.w;
    }
    const int b_ = row / NN, n = row % NN;
    const int hh = tid / HD, hd = tid % HD;
    const size_t idx = ((size_t)(b_ * NH + hh) * NN + n) * HD + hd;
    qo[idx] = aq;
    ko[idx] = ak;
    vo[idx] = av;
}

// ---------- K2: flash attention, 4-way split-K per block ----------
// grid = (N/64, B*NH), block = 256 (4 waves). wave w handles keys [w*1024,(w+1)*1024)
__global__ __launch_bounds__(256) void k_attn(
    const float* __restrict__ q, const float* __restrict__ k, const float* __restrict__ v,
    float* __restrict__ ctx) {
    __shared__ float st[4 * 64 * 36];     // merge buffer: [wave][row][36] (m,l,acc[32])

    const int lane = threadIdx.x & 63;
    const int w = threadIdx.x >> 6;
    const int bh = blockIdx.y;
    const int row = blockIdx.x * 64 + lane;

    // load q row into registers
    const float* qp = q + ((size_t)bh * NN + row) * HD;
    float qr[HD];
    #pragma unroll
    for (int i = 0; i < HD / 4; ++i) {
        float4 t = ((const float4*)qp)[i];
        qr[4 * i + 0] = t.x; qr[4 * i + 1] = t.y; qr[4 * i + 2] = t.z; qr[4 * i + 3] = t.w;
    }
    const float scale = 0.17677669529663687f;   // 32^-0.5

    float m = -1e30f, l = 0.f;
    float acc[HD];
    #pragma unroll
    for (int i = 0; i < HD; ++i) acc[i] = 0.f;

    const float* kbase = k + (size_t)bh * NN * HD;
    const float* vbase = v + (size_t)bh * NN * HD;
    const int k0 = __builtin_amdgcn_readfirstlane(w) * (NN / 4);  // wave-uniform key base

    for (int t = 0; t < NN / 4; t += 8) {
        // 8 dots
        float dots[8];
        #pragma unroll
        for (int j = 0; j < 8; ++j) {
            const float4* kr = (const float4*)(kbase + (size_t)(k0 + t + j) * HD);
            float dd = 0.f;
            #pragma unroll
            for (int i = 0; i < HD / 4; ++i) {
                float4 kk = kr[i];
                dd += qr[4 * i + 0] * kk.x + qr[4 * i + 1] * kk.y +
                      qr[4 * i + 2] * kk.z + qr[4 * i + 3] * kk.w;
            }
            dots[j] = dd * scale;
        }
        // tile max + single rescale
        float tm = dots[0];
        #pragma unroll
        for (int j = 1; j < 8; ++j) tm = fmaxf(tm, dots[j]);
        float mn = fmaxf(m, tm);
        float c = __expf(m - mn);
        m = mn;
        l *= c;
        #pragma unroll
        for (int i = 0; i < HD; ++i) acc[i] *= c;
        // accumulate PV
        #pragma unroll
        for (int j = 0; j < 8; ++j) {
            float p = __expf(dots[j] - mn);
            l += p;
            const float4* vr = (const float4*)(vbase + (size_t)(k0 + t + j) * HD);
            #pragma unroll
            for (int i = 0; i < HD / 4; ++i) {
                float4 vv = vr[i];
                acc[4 * i + 0] += p * vv.x; acc[4 * i + 1] += p * vv.y;
                acc[4 * i + 2] += p * vv.z; acc[4 * i + 3] += p * vv.w;
            }
        }
    }

    // write per-wave state
    float* stp = st + (size_t)(w * 64 + lane) * 36;
    stp[0] = m;
    stp[1] = l;
    #pragma unroll
    for (int i = 0; i < HD; ++i) stp[2 + i] = acc[i];
    __syncthreads();

    // wave 0 merges the 4 partial states per row
    if (w == 0) {
        float M = st[(size_t)(0 * 64 + lane) * 36];
        #pragma unroll
        for (int ww = 1; ww < 4; ++ww) M = fmaxf(M, st[(size_t)(ww * 64 + lane) * 36]);
        float L = 0.f;
        float o[HD];
        #pragma unroll
        for (int i = 0; i < HD; ++i) o[i] = 0.f;
        #pragma unroll
        for (int ww = 0; ww < 4; ++ww) {
            const float* sp = st + (size_t)(ww * 64 + lane) * 36;
            float e = __expf(sp[0] - M);
            L += sp[1] * e;
            #pragma unroll
            for (int i = 0; i < HD; ++i) o[i] += e * sp[2 + i];
        }
        float inv = 1.0f / L;
        const int b_ = bh / NH, h_ = bh % NH;
        float* op = ctx + ((size_t)b_ * NN + row) * NC + h_ * HD;
        #pragma unroll
        for (int i = 0; i < HD; ++i) op[i] = o[i] * inv;
    }
}

// ---------- K3: proj + residual + LN2 ----------
// grid = B*N, block = 128
__global__ __launch_bounds__(128) void k_proj_ln2(
    const float* __restrict__ ctx, const float* __restrict__ x,
    const float* __restrict__ proj_w, const float* __restrict__ proj_b,
    const float* __restrict__ ln_w, const float* __restrict__ ln_b,
    float* __restrict__ x2, float* __restrict__ h2) {
    __shared__ float sc[NC];
    __shared__ float sred[2];
    const int row = blockIdx.x, tid = threadIdx.x;
    sc[tid] = ctx[(size_t)row * NC + tid];
    __syncthreads();
    const float4* c4 = (const float4*)sc;
    const float4* w4 = (const float4*)(proj_w + (size_t)tid * NC);
    float a = 0.f;
    #pragma unroll
    for (int c = 0; c < NC / 4; ++c) {
        float4 h = c4[c], w = w4[c];
        a += h.x * w.x + h.y * w.y + h.z * w.z + h.w * w.w;
    }
    float xv = x[(size_t)row * NC + tid] + a + proj_b[tid];
    float mean = block_reduce_sum_128(xv, sred, tid) * (1.0f / NC);
    float d = xv - mean;
    float var = block_reduce_sum_128(d * d, sred, tid) * (1.0f / NC);
    float hv = d * rsqrtf(var + EPS) * ln_w[tid] + ln_b[tid];
    x2[(size_t)row * NC + tid] = xv;
    h2[(size_t)row * NC + tid] = hv;
}

// ---------- K4: conv1 1x1 (C -> 2C) ----------
// grid = B*N, block = 256
__global__ __launch_bounds__(256) void k_conv1(
    const float* __restrict__ h2, const float* __restrict__ w1, const float* __restrict__ b1,
    float* __restrict__ x1) {
    __shared__ float sh[NC];
    const int row = blockIdx.x, tid = threadIdx.x;
    if (tid < NC) sh[tid] = h2[(size_t)row * NC + tid];
    __syncthreads();
    const float4* h4 = (const float4*)sh;
    const float4* w4 = (const float4*)(w1 + (size_t)tid * NC);
    float a = 0.f;
    #pragma unroll
    for (int c = 0; c < NC / 4; ++c) {
        float4 h = h4[c], w = w4[c];
        a += h.x * w.x + h.y * w.y + h.z * w.z + h.w * w.w;
    }
    x1[(size_t)row * C2 + tid] = a + b1[tid];
}

// ---------- K5: dw3x3 + dw5x5 + sum + SimpleGate ----------
// grid = B*4096 pixels, block = 128 (thread = channel c of the gate pair)
__global__ __launch_bounds__(128) void k_dwgate(
    const float* __restrict__ x1,
    const float* __restrict__ w33, const float* __restrict__ b33,
    const float* __restrict__ w55, const float* __restrict__ b55,
    float* __restrict__ gated) {
    const int pb = blockIdx.x;      // b*4096 + p
    const int c = threadIdx.x;      // 0..127
    const int b_ = pb >> 12, p = pb & 4095;
    const int py = p >> 6, px = p & 63;
    const float* base = x1 + (size_t)b_ * NN * C2;

    float a5 = 0.f, g5 = 0.f, a3 = 0.f, g3 = 0.f;
    float ctr_a = 0.f, ctr_g = 0.f;
    #pragma unroll
    for (int dy = -2; dy <= 2; ++dy) {
        const int yy = py + dy;
        #pragma unroll
        for (int dx = -2; dx <= 2; ++dx) {
            const int xx = px + dx;
            const bool in = (yy >= 0) && (yy < HW) && (xx >= 0) && (xx < HW);
            const size_t off = (size_t)(yy * HW + xx) * C2;
            float xa = in ? base[off + c] : 0.f;
            float xg = in ? base[off + NC + c] : 0.f;
            const int k5 = (dy + 2) * 5 + (dx + 2);
            a5 += xa * w55[c * 25 + k5];
            g5 += xg * w55[(NC + c) * 25 + k5];
            if (dy >= -1 && dy <= 1 && dx >= -1 && dx <= 1) {
                const int k3 = (dy + 1) * 3 + (dx + 1);
                a3 += xa * w33[c * 9 + k3];
                g3 += xg * w33[(NC + c) * 9 + k3];
            }
            if (dy == 0 && dx == 0) { ctr_a = xa; ctr_g = xg; }
        }
    }
    float sa = ctr_a + a3 + b33[c] + a5 + b55[c];
    float sg = ctr_g + g3 + b33[NC + c] + g5 + b55[NC + c];
    gated[(size_t)pb * NC + c] = sa * sg;
}

// ---------- K6: conv4 1x1 + final residual ----------
// grid = B*N, block = 128
__global__ __launch_bounds__(128) void k_conv4(
    const float* __restrict__ gated, const float* __restrict__ w4_, const float* __restrict__ b4,
    const float* __restrict__ x2, float* __restrict__ out) {
    __shared__ float sg[NC];
    const int row = blockIdx.x, tid = threadIdx.x;
    sg[tid] = gated[(size_t)row * NC + tid];
    __syncthreads();
    const float4* h4 = (const float4*)sg;
    const float4* w4 = (const float4*)(w4_ + (size_t)tid * NC);
    float a = 0.f;
    #pragma unroll
    for (int c = 0; c < NC / 4; ++c) {
        float4 h = h4[c], w = w4[c];
        a += h.x * w.x + h.y * w.y + h.z * w.z + h.w * w.w;
    }
    out[(size_t)row * NC + tid] = x2[(size_t)row * NC + tid] + a + b4[tid];
}

// ---------- launcher ----------
extern "C" void kernel_launch(void* const* d_in, const int* in_sizes, int n_in,
                              void* d_out, int out_size, void* d_ws, size_t ws_size,
                              hipStream_t stream) {
    const float* x      = (const float*)d_in[0];
    // d_in[1] = H, d_in[2] = W (ints, hardcoded 64)
    const float* ln1_w  = (const float*)d_in[3];
    const float* ln1_b  = (const float*)d_in[4];
    const float* q_w    = (const float*)d_in[5];
    const float* kv_w   = (const float*)d_in[6];
    const float* proj_w = (const float*)d_in[7];
    const float* proj_b = (const float*)d_in[8];
    const float* ln2_w  = (const float*)d_in[9];
    const float* ln2_b  = (const float*)d_in[10];
    const float* c1_w   = (const float*)d_in[11];
    const float* c1_b   = (const float*)d_in[12];
    const float* c33_w  = (const float*)d_in[13];
    const float* c33_b  = (const float*)d_in[14];
    const float* c55_w  = (const float*)d_in[15];
    const float* c55_b  = (const float*)d_in[16];
    const float* c4_w   = (const float*)d_in[17];
    const float* c4_b   = (const float*)d_in[18];

    float* ws = (float*)d_ws;
    const size_t M = 1u << 20;     // 1M floats
    float* qb    = ws;             // [B*NH][NN][HD]  1M
    float* kb    = ws + 1 * M;     // 1M
    float* vb    = ws + 2 * M;     // 1M
    float* ctx   = ws + 3 * M;     // [B][NN][NC]     1M
    float* x2    = ws + 4 * M;     // 1M
    float* h2    = ws + 5 * M;     // 1M
    float* x1    = ws + 6 * M;     // [B][NN][C2]     2M
    float* gated = ws + 8 * M;     // [B][NN][NC]     1M
    float* out   = (float*)d_out;

    k_ln_qkv<<<NB * NN, 128, 0, stream>>>(x, ln1_w, ln1_b, q_w, kv_w, qb, kb, vb);
    k_attn<<<dim3(NN / 64, NB * NH), 256, 0, stream>>>(qb, kb, vb, ctx);
    k_proj_ln2<<<NB * NN, 128, 0, stream>>>(ctx, x, proj_w, proj_b, ln2_w, ln2_b, x2, h2);
    k_conv1<<<NB * NN, 256, 0, stream>>>(h2, c1_w, c1_b, x1);
    k_dwgate<<<NB * NN, 128, 0, stream>>>(x1, c33_w, c33_b, c55_w, c55_b, gated);
    k_conv4<<<NB * NN, 128, 0, stream>>>(gated, c4_w, c4_b, x2, out);
}

// Round 4
// 209.880 us; speedup vs baseline: 7.1637x; 7.1637x over previous
//
#include <hip/hip_runtime.h>
#include <hip/hip_bf16.h>
#include <math.h>

#define NB 2
#define NN 4096
#define NC 128
#define NH 4
#define HD 32
#define C2 256
#define HW 64
#define EPS 1e-5f

typedef unsigned short u16;
typedef short bf16x8 __attribute__((ext_vector_type(8)));      // 8 bf16 = 4 VGPRs
typedef unsigned short u16x8 __attribute__((ext_vector_type(8)));
typedef float f32x16 __attribute__((ext_vector_type(16)));

__device__ __forceinline__ u16 f2b(float x) {
    return __bfloat16_as_ushort(__float2bfloat16(x));
}
__device__ __forceinline__ unsigned pack_bf16(float a, float b) {
    return (unsigned)f2b(a) | ((unsigned)f2b(b) << 16);
}
__device__ __forceinline__ f32x16 fzero16() {
    f32x16 z;
    #pragma unroll
    for (int i = 0; i < 16; ++i) z[i] = 0.f;
    return z;
}
union U32x4 { unsigned u[4]; bf16x8 v; };

__device__ __forceinline__ float block_reduce_sum_128(float v, float* sbuf, int tid) {
    #pragma unroll
    for (int off = 32; off > 0; off >>= 1) v += __shfl_xor(v, off, 64);
    __syncthreads();
    if ((tid & 63) == 0) sbuf[tid >> 6] = v;
    __syncthreads();
    return sbuf[0] + sbuf[1];
}

// ---------- K0: weight prep (f32 -> bf16, dw-weight transpose) ----------
__global__ void k_prep(const float* __restrict__ q_w, const float* __restrict__ kv_w,
                       const float* __restrict__ proj_w, const float* __restrict__ c1_w,
                       const float* __restrict__ c4_w, const float* __restrict__ c33_w,
                       const float* __restrict__ c55_w,
                       u16* wqkv, u16* wproj, u16* wc1, u16* wc4,
                       float* wt33, float* wt55) {
    const int tid = blockIdx.x * blockDim.x + threadIdx.x;
    const int nth = gridDim.x * blockDim.x;
    const float s = 0.17677669529663687f;   // 1/sqrt(32), folded into q weights
    for (int i = tid; i < 128 * 128; i += nth) wqkv[i] = f2b(q_w[i] * s);
    for (int i = tid; i < 256 * 128; i += nth) wqkv[128 * 128 + i] = f2b(kv_w[i]);
    for (int i = tid; i < 128 * 128; i += nth) wproj[i] = f2b(proj_w[i]);
    for (int i = tid; i < 256 * 128; i += nth) wc1[i] = f2b(c1_w[i]);
    for (int i = tid; i < 128 * 128; i += nth) wc4[i] = f2b(c4_w[i]);
    for (int i = tid; i < 9 * 256; i += nth)  { int k = i >> 8, c = i & 255; wt33[i] = c33_w[c * 9 + k]; }
    for (int i = tid; i < 25 * 256; i += nth) { int k = i / 256, c = i % 256; wt55[i] = c55_w[c * 25 + k]; }
}

// ---------- K1: LN (f32 in -> bf16 out) ----------
__global__ __launch_bounds__(128) void k_ln(
    const float* __restrict__ x, const float* __restrict__ w, const float* __restrict__ b,
    u16* __restrict__ h) {
    __shared__ float sred[2];
    const int row = blockIdx.x, tid = threadIdx.x;
    float xv = x[(size_t)row * NC + tid];
    float mean = block_reduce_sum_128(xv, sred, tid) * (1.0f / NC);
    float d = xv - mean;
    float var = block_reduce_sum_128(d * d, sred, tid) * (1.0f / NC);
    float hv = d * rsqrtf(var + EPS) * w[tid] + b[tid];
    h[(size_t)row * NC + tid] = f2b(hv);
}

// ---------- shared GEMM core: one wave -> 32x32 tile, K=128 ----------
__device__ __forceinline__ f32x16 gemm_tile_32x32(
    const u16* __restrict__ A, const u16* __restrict__ W, int m0, int n0, int q, int h5) {
    const u16* ap = A + (size_t)(m0 + q) * 128 + h5 * 8;
    const u16* wp = W + (size_t)(n0 + q) * 128 + h5 * 8;
    f32x16 acc = fzero16();
    #pragma unroll
    for (int kk = 0; kk < 8; ++kk) {
        bf16x8 af = *(const bf16x8*)(ap + kk * 16);
        bf16x8 wf = *(const bf16x8*)(wp + kk * 16);
        acc = __builtin_amdgcn_mfma_f32_32x32x16_bf16(af, wf, acc, 0, 0, 0);
    }
    return acc;
}
#define GEMM_PROLOG(NCOLS)                                    \
    const int l = threadIdx.x & 63, wid = threadIdx.x >> 6;   \
    const int q = l & 31, h5 = l >> 5;                        \
    const int m0 = blockIdx.x * 64 + (wid >> 1) * 32;         \
    const int n0 = blockIdx.y * 64 + (wid & 1) * 32;          \
    const int o = n0 + q;                                     \
    (void)o;

// ---------- K2: QKV projection GEMM (N=384) ----------
__global__ __launch_bounds__(256) void k_gemm_qkv(
    const u16* __restrict__ h1, const u16* __restrict__ wqkv,
    u16* __restrict__ qb, u16* __restrict__ kbuf, u16* __restrict__ vb) {
    GEMM_PROLOG(384)
    f32x16 acc = gemm_tile_32x32(h1, wqkv, m0, n0, q, h5);
    #pragma unroll
    for (int r = 0; r < 16; ++r) {
        const int mr = m0 + (r & 3) + 8 * (r >> 2) + 4 * h5;
        const int b_ = mr >> 12, n = mr & 4095;
        const u16 val = f2b(acc[r]);
        if (o < 128) {
            qb[((size_t)(b_ * 4 + (o >> 5)) * NN + n) * HD + (o & 31)] = val;
        } else if (o < 256) {
            const int o2 = o - 128;
            kbuf[((size_t)(b_ * 4 + (o2 >> 5)) * NN + n) * HD + (o2 & 31)] = val;
        } else {
            vb[(size_t)mr * 128 + (o - 256)] = val;
        }
    }
}

// ---------- K3: V transpose -> VT[bh][d][n] ----------
__global__ __launch_bounds__(256) void k_vt(const u16* __restrict__ vb, u16* __restrict__ vtb) {
    __shared__ u16 lds[32][64];
    const int t = threadIdx.x;
    const int bh = blockIdx.y, b_ = bh >> 2, hh = bh & 3;
    const int n0 = blockIdx.x * 64;
    {
        const int i = t >> 2, d0 = (t & 3) * 8;
        u16x8 v = *(const u16x8*)(vb + (size_t)(b_ * NN + n0 + i) * 128 + hh * 32 + d0);
        #pragma unroll
        for (int j = 0; j < 8; ++j) lds[d0 + j][i] = v[j];
    }
    __syncthreads();
    {
        const int d = t >> 3, j0 = (t & 7) * 8;
        u16x8 v;
        #pragma unroll
        for (int u = 0; u < 8; ++u) v[u] = lds[d][j0 + u];
        *(u16x8*)(vtb + ((size_t)bh * 32 + d) * NN + n0 + j0) = v;
    }
}

// ---------- K4: MFMA flash attention ----------
// grid = (NN/32, NB*NH), block = 256 (4 waves, split-K: wave w owns keys [w*1024, w*1024+1024))
__global__ __launch_bounds__(256) void k_attn(
    const u16* __restrict__ qb, const u16* __restrict__ kbuf, const u16* __restrict__ vtb,
    u16* __restrict__ ctxb) {
    __shared__ float smx[4][32];
    __shared__ float slv[4][32];
    __shared__ float so[4][64][17];

    const int l = threadIdx.x & 63, w = threadIdx.x >> 6;
    const int q = l & 31, h5 = l >> 5;
    const int bh = blockIdx.y;
    const int qbase = blockIdx.x * 32;

    // Q B-fragments (scale pre-folded into weights)
    const u16* qp = qb + ((size_t)bh * NN + qbase + q) * HD + h5 * 8;
    const bf16x8 qf0 = *(const bf16x8*)qp;
    const bf16x8 qf1 = *(const bf16x8*)(qp + 16);

    const int kb0 = w * 1024;
    const u16* kp = kbuf + ((size_t)bh * NN + kb0 + q) * HD + h5 * 8;
    const u16* vp = vtb + ((size_t)bh * 32 + q) * NN + kb0 + h5 * 8;

    float m = -INFINITY, lacc = 0.f;
    f32x16 O = fzero16();

    for (int t = 0; t < 32; ++t) {
        const bf16x8 kf0 = *(const bf16x8*)kp;
        const bf16x8 kf1 = *(const bf16x8*)(kp + 16);
        const bf16x8 vf0 = *(const bf16x8*)vp;
        const bf16x8 vf1 = *(const bf16x8*)(vp + 16);
        kp += 32 * HD;   // 32 keys
        vp += 32;

        // S^T[key][q] = K_tile . Q^T  (two d-halves)
        f32x16 s = fzero16();
        s = __builtin_amdgcn_mfma_f32_32x32x16_bf16(kf0, qf0, s, 0, 0, 0);
        s = __builtin_amdgcn_mfma_f32_32x32x16_bf16(kf1, qf1, s, 0, 0, 0);

        // tile max across the 32 keys of this lane's q (own 16 + partner 16)
        float tm = s[0];
        #pragma unroll
        for (int r = 1; r < 16; ++r) tm = fmaxf(tm, s[r]);
        tm = fmaxf(tm, __shfl_xor(tm, 32));

        // defer-max rescale (rare after first tile)
        if (__any(tm > m + 8.0f)) {
            const float mn = fmaxf(m, tm);
            const float f = __expf(m - mn);
            lacc *= f;
            #pragma unroll
            for (int r = 0; r < 16; ++r) {
                const float fr = __shfl(f, (r & 3) + 8 * (r >> 2) + 4 * h5);
                O[r] *= fr;
            }
            m = mn;
        }

        float p[16];
        float ls = 0.f;
        #pragma unroll
        for (int r = 0; r < 16; ++r) { p[r] = __expf(s[r] - m); ls += p[r]; }
        ls += __shfl_xor(ls, 32);
        lacc += ls;

        // pack P to bf16 pairs, exchange halves, assemble PV A-fragments
        unsigned pk[8], ok[8];
        #pragma unroll
        for (int i = 0; i < 8; ++i) pk[i] = pack_bf16(p[2 * i], p[2 * i + 1]);
        #pragma unroll
        for (int i = 0; i < 8; ++i) ok[i] = __shfl_xor(pk[i], 32);

        U32x4 a0, a1;
        if (h5 == 0) {
            a0.u[0] = pk[0]; a0.u[1] = pk[1]; a0.u[2] = ok[0]; a0.u[3] = ok[1];
            a1.u[0] = pk[4]; a1.u[1] = pk[5]; a1.u[2] = ok[4]; a1.u[3] = ok[5];
        } else {
            a0.u[0] = ok[2]; a0.u[1] = ok[3]; a0.u[2] = pk[2]; a0.u[3] = pk[3];
            a1.u[0] = ok[6]; a1.u[1] = ok[7]; a1.u[2] = pk[6]; a1.u[3] = pk[7];
        }
        O = __builtin_amdgcn_mfma_f32_32x32x16_bf16(a0.v, vf0, O, 0, 0, 0);
        O = __builtin_amdgcn_mfma_f32_32x32x16_bf16(a1.v, vf1, O, 0, 0, 0);
    }

    // ---- split-K merge across the 4 waves ----
    if (l < 32) smx[w][l] = m;
    __syncthreads();
    const float M = fmaxf(fmaxf(smx[0][q], smx[1][q]), fmaxf(smx[2][q], smx[3][q]));
    const float g = __expf(m - M);
    if (l < 32) slv[w][l] = lacc * g;
    #pragma unroll
    for (int r = 0; r < 16; ++r) {
        const float gr = __shfl(g, (r & 3) + 8 * (r >> 2) + 4 * h5);
        so[w][l][r] = O[r] * gr;
    }
    __syncthreads();

    const float Lq = slv[0][q] + slv[1][q] + slv[2][q] + slv[3][q];
    const float linv = 1.0f / Lq;
    const int b_ = bh >> 2, h_ = bh & 3;
    #pragma unroll
    for (int i = 0; i < 4; ++i) {
        const int r = 4 * w + i;
        const float os = so[0][l][r] + so[1][l][r] + so[2][l][r] + so[3][l][r];
        const int qr = (r & 3) + 8 * (r >> 2) + 4 * h5;
        const float fr = __shfl(linv, qr);
        ctxb[((size_t)(b_ * NN + qbase + qr)) * NC + h_ * 32 + q] = f2b(os * fr);
    }
}

// ---------- K5: proj GEMM + bias + residual -> x2 (f32) ----------
__global__ __launch_bounds__(256) void k_gemm_proj(
    const u16* __restrict__ ctxb, const u16* __restrict__ wproj,
    const float* __restrict__ pbias, const float* __restrict__ x, float* __restrict__ x2) {
    GEMM_PROLOG(128)
    f32x16 acc = gemm_tile_32x32(ctxb, wproj, m0, n0, q, h5);
    const float bo = pbias[o];
    #pragma unroll
    for (int r = 0; r < 16; ++r) {
        const int mr = m0 + (r & 3) + 8 * (r >> 2) + 4 * h5;
        x2[(size_t)mr * 128 + o] = acc[r] + bo + x[(size_t)mr * 128 + o];
    }
}

// ---------- K6: conv1 GEMM (N=256) + bias -> x1 (f32) ----------
__global__ __launch_bounds__(256) void k_gemm_c1(
    const u16* __restrict__ h2, const u16* __restrict__ wc1,
    const float* __restrict__ bias, float* __restrict__ x1) {
    GEMM_PROLOG(256)
    f32x16 acc = gemm_tile_32x32(h2, wc1, m0, n0, q, h5);
    const float bo = bias[o];
    #pragma unroll
    for (int r = 0; r < 16; ++r) {
        const int mr = m0 + (r & 3) + 8 * (r >> 2) + 4 * h5;
        x1[(size_t)mr * 256 + o] = acc[r] + bo;
    }
}

// ---------- K7: dw3x3 + dw5x5 + SimpleGate (transposed weights) ----------
__global__ __launch_bounds__(128) void k_dwgate(
    const float* __restrict__ x1, const float* __restrict__ wt33, const float* __restrict__ wt55,
    const float* __restrict__ b33, const float* __restrict__ b55, u16* __restrict__ gatedb) {
    const int pb = blockIdx.x, c = threadIdx.x;
    const int b_ = pb >> 12, p = pb & 4095;
    const int py = p >> 6, px = p & 63;
    const float* base = x1 + (size_t)b_ * NN * C2;

    float a5 = 0.f, g5 = 0.f, a3 = 0.f, g3 = 0.f, ca = 0.f, cg = 0.f;
    #pragma unroll
    for (int dy = -2; dy <= 2; ++dy) {
        const int yy = py + dy;
        #pragma unroll
        for (int dx = -2; dx <= 2; ++dx) {
            const int xx = px + dx;
            const bool in = (yy >= 0) && (yy < HW) && (xx >= 0) && (xx < HW);
            const size_t off = (size_t)(yy * HW + xx) * C2;
            const float xa = in ? base[off + c] : 0.f;
            const float xg = in ? base[off + 128 + c] : 0.f;
            const int k5 = (dy + 2) * 5 + (dx + 2);
            a5 += xa * wt55[k5 * 256 + c];
            g5 += xg * wt55[k5 * 256 + 128 + c];
            if (dy >= -1 && dy <= 1 && dx >= -1 && dx <= 1) {
                const int k3 = (dy + 1) * 3 + (dx + 1);
                a3 += xa * wt33[k3 * 256 + c];
                g3 += xg * wt33[k3 * 256 + 128 + c];
            }
            if (dy == 0 && dx == 0) { ca = xa; cg = xg; }
        }
    }
    const float sa = ca + a3 + b33[c] + a5 + b55[c];
    const float sg = cg + g3 + b33[128 + c] + g5 + b55[128 + c];
    gatedb[(size_t)pb * 128 + c] = f2b(sa * sg);
}

// ---------- K8: conv4 GEMM + bias + residual -> out (f32) ----------
__global__ __launch_bounds__(256) void k_gemm_c4(
    const u16* __restrict__ gatedb, const u16* __restrict__ wc4,
    const float* __restrict__ bias, const float* __restrict__ x2, float* __restrict__ out) {
    GEMM_PROLOG(128)
    f32x16 acc = gemm_tile_32x32(gatedb, wc4, m0, n0, q, h5);
    const float bo = bias[o];
    #pragma unroll
    for (int r = 0; r < 16; ++r) {
        const int mr = m0 + (r & 3) + 8 * (r >> 2) + 4 * h5;
        out[(size_t)mr * 128 + o] = acc[r] + bo + x2[(size_t)mr * 128 + o];
    }
}

// ---------- launcher ----------
extern "C" void kernel_launch(void* const* d_in, const int* in_sizes, int n_in,
                              void* d_out, int out_size, void* d_ws, size_t ws_size,
                              hipStream_t stream) {
    const float* x      = (const float*)d_in[0];
    const float* ln1_w  = (const float*)d_in[3];
    const float* ln1_b  = (const float*)d_in[4];
    const float* q_w    = (const float*)d_in[5];
    const float* kv_w   = (const float*)d_in[6];
    const float* proj_w = (const float*)d_in[7];
    const float* proj_b = (const float*)d_in[8];
    const float* ln2_w  = (const float*)d_in[9];
    const float* ln2_b  = (const float*)d_in[10];
    const float* c1_w   = (const float*)d_in[11];
    const float* c1_b   = (const float*)d_in[12];
    const float* c33_w  = (const float*)d_in[13];
    const float* c33_b  = (const float*)d_in[14];
    const float* c55_w  = (const float*)d_in[15];
    const float* c55_b  = (const float*)d_in[16];
    const float* c4_w   = (const float*)d_in[17];
    const float* c4_b   = (const float*)d_in[18];

    char* p = (char*)d_ws;
    u16*   wqkv  = (u16*)p;   p += 384 * 128 * 2;
    u16*   wproj = (u16*)p;   p += 128 * 128 * 2;
    u16*   wc1   = (u16*)p;   p += 256 * 128 * 2;
    u16*   wc4   = (u16*)p;   p += 128 * 128 * 2;
    float* wt33  = (float*)p; p += 9 * 256 * 4;
    float* wt55  = (float*)p; p += 25 * 256 * 4;
    u16*   h1    = (u16*)p;   p += (size_t)8192 * 128 * 2;
    u16*   qb    = (u16*)p;   p += (size_t)8 * 4096 * 32 * 2;
    u16*   kb    = (u16*)p;   p += (size_t)8 * 4096 * 32 * 2;
    u16*   vb    = (u16*)p;   p += (size_t)8192 * 128 * 2;
    u16*   vtb   = (u16*)p;   p += (size_t)8 * 32 * 4096 * 2;
    u16*   ctxb  = (u16*)p;   p += (size_t)8192 * 128 * 2;
    float* x2    = (float*)p; p += (size_t)8192 * 128 * 4;
    u16*   h2    = (u16*)p;   p += (size_t)8192 * 128 * 2;
    float* x1    = (float*)p; p += (size_t)8192 * 256 * 4;
    u16*   gatedb= (u16*)p;   p += (size_t)8192 * 128 * 2;
    float* out   = (float*)d_out;

    k_prep<<<64, 256, 0, stream>>>(q_w, kv_w, proj_w, c1_w, c4_w, c33_w, c55_w,
                                   wqkv, wproj, wc1, wc4, wt33, wt55);
    k_ln<<<NB * NN, 128, 0, stream>>>(x, ln1_w, ln1_b, h1);
    k_gemm_qkv<<<dim3(128, 6), 256, 0, stream>>>(h1, wqkv, qb, kb, vb);
    k_vt<<<dim3(64, 8), 256, 0, stream>>>(vb, vtb);
    k_attn<<<dim3(NN / 32, NB * NH), 256, 0, stream>>>(qb, kb, vtb, ctxb);
    k_gemm_proj<<<dim3(128, 2), 256, 0, stream>>>(ctxb, wproj, proj_b, x, x2);
    k_ln<<<NB * NN, 128, 0, stream>>>(x2, ln2_w, ln2_b, h2);
    k_gemm_c1<<<dim3(128, 4), 256, 0, stream>>>(h2, wc1, c1_b, x1);
    k_dwgate<<<NB * NN, 128, 0, stream>>>(x1, wt33, wt55, c33_b, c55_b, gatedb);
    k_gemm_c4<<<dim3(128, 2), 256, 0, stream>>>(gatedb, wc4, c4_b, x2, out);
}

// Round 5
// 199.821 us; speedup vs baseline: 7.5243x; 1.0503x over previous
//
#include <hip/hip_runtime.h>
#include <hip/hip_bf16.h>
#include <math.h>

#define NB 2
#define NN 4096
#define NC 128
#define NH 4
#define HD 32
#define C2 256
#define HW 64
#define EPS 1e-5f

typedef unsigned short u16;
typedef short bf16x8 __attribute__((ext_vector_type(8)));      // 8 bf16 = 4 VGPRs
typedef unsigned short u16x8 __attribute__((ext_vector_type(8)));
typedef float f32x16 __attribute__((ext_vector_type(16)));

__device__ __forceinline__ u16 f2b(float x) {
    return __bfloat16_as_ushort(__float2bfloat16(x));
}
__device__ __forceinline__ unsigned pack_bf16(float a, float b) {
    return (unsigned)f2b(a) | ((unsigned)f2b(b) << 16);
}
__device__ __forceinline__ f32x16 fzero16() {
    f32x16 z;
    #pragma unroll
    for (int i = 0; i < 16; ++i) z[i] = 0.f;
    return z;
}
union U32x4 { unsigned u[4]; bf16x8 v; };

// lane<->lane+32 half swap, pure VALU (no LDS)
__device__ __forceinline__ void plswap(unsigned& a, unsigned& b) {
    asm("v_permlane32_swap_b32 %0, %1" : "+v"(a), "+v"(b));
}
// returns partner-half's value of v (h5 = lane>>5)
__device__ __forceinline__ float xswap(float v, int h5) {
    float a = v, b = v;
    asm("v_permlane32_swap_b32 %0, %1" : "+v"(a), "+v"(b));
    return h5 ? a : b;      // lanes<32: partner in b; lanes>=32: partner in a
}

// ---------- K0: weight prep (f32 -> bf16, dw-weight transpose) ----------
__global__ void k_prep(const float* __restrict__ q_w, const float* __restrict__ kv_w,
                       const float* __restrict__ proj_w, const float* __restrict__ c1_w,
                       const float* __restrict__ c4_w, const float* __restrict__ c33_w,
                       const float* __restrict__ c55_w,
                       u16* wqkv, u16* wproj, u16* wc1, u16* wc4,
                       float* wt33, float* wt55) {
    const int tid = blockIdx.x * blockDim.x + threadIdx.x;
    const int nth = gridDim.x * blockDim.x;
    // fold 1/sqrt(32) AND log2(e) into q weights -> attention works in exp2 domain
    const float s = 0.17677669529663687f * 1.4426950408889634f;
    for (int i = tid; i < 128 * 128; i += nth) wqkv[i] = f2b(q_w[i] * s);
    for (int i = tid; i < 256 * 128; i += nth) wqkv[128 * 128 + i] = f2b(kv_w[i]);
    for (int i = tid; i < 128 * 128; i += nth) wproj[i] = f2b(proj_w[i]);
    for (int i = tid; i < 256 * 128; i += nth) wc1[i] = f2b(c1_w[i]);
    for (int i = tid; i < 128 * 128; i += nth) wc4[i] = f2b(c4_w[i]);
    for (int i = tid; i < 9 * 256; i += nth)  { int k = i >> 8, c = i & 255; wt33[i] = c33_w[c * 9 + k]; }
    for (int i = tid; i < 25 * 256; i += nth) { int k = i / 256, c = i % 256; wt55[i] = c55_w[c * 25 + k]; }
}

// ---------- K1: LN1 (f32 in -> bf16 out), one wave per row ----------
__global__ __launch_bounds__(256) void k_ln(
    const float* __restrict__ x, const float* __restrict__ w, const float* __restrict__ b,
    u16* __restrict__ h) {
    const int l = threadIdx.x & 63, wid = threadIdx.x >> 6;
    const int row = blockIdx.x * 4 + wid;
    const float2 xv = *(const float2*)(x + (size_t)row * NC + l * 2);
    float sum = xv.x + xv.y, ss = xv.x * xv.x + xv.y * xv.y;
    #pragma unroll
    for (int off = 1; off < 64; off <<= 1) {
        sum += __shfl_xor(sum, off);
        ss  += __shfl_xor(ss, off);
    }
    const float mean = sum * (1.0f / NC);
    const float var  = ss * (1.0f / NC) - mean * mean;
    const float rstd = rsqrtf(var + EPS);
    const float2 wv = *(const float2*)(w + l * 2);
    const float2 bv = *(const float2*)(b + l * 2);
    const float h0 = (xv.x - mean) * rstd * wv.x + bv.x;
    const float h1 = (xv.y - mean) * rstd * wv.y + bv.y;
    *(unsigned*)(h + (size_t)row * NC + l * 2) = pack_bf16(h0, h1);
}

// ---------- shared GEMM core: one wave -> 32x32 tile, K=128 ----------
__device__ __forceinline__ f32x16 gemm_tile_32x32(
    const u16* __restrict__ A, const u16* __restrict__ W, int m0, int n0, int q, int h5) {
    const u16* ap = A + (size_t)(m0 + q) * 128 + h5 * 8;
    const u16* wp = W + (size_t)(n0 + q) * 128 + h5 * 8;
    f32x16 acc = fzero16();
    #pragma unroll
    for (int kk = 0; kk < 8; ++kk) {
        bf16x8 af = *(const bf16x8*)(ap + kk * 16);
        bf16x8 wf = *(const bf16x8*)(wp + kk * 16);
        acc = __builtin_amdgcn_mfma_f32_32x32x16_bf16(af, wf, acc, 0, 0, 0);
    }
    return acc;
}
#define GEMM_PROLOG(NCOLS)                                    \
    const int l = threadIdx.x & 63, wid = threadIdx.x >> 6;   \
    const int q = l & 31, h5 = l >> 5;                        \
    const int m0 = blockIdx.x * 64 + (wid >> 1) * 32;         \
    const int n0 = blockIdx.y * 64 + (wid & 1) * 32;          \
    const int o = n0 + q;                                     \
    (void)o;

// ---------- K2: QKV projection GEMM (N=384) ----------
__global__ __launch_bounds__(256) void k_gemm_qkv(
    const u16* __restrict__ h1, const u16* __restrict__ wqkv,
    u16* __restrict__ qb, u16* __restrict__ kbuf, u16* __restrict__ vb) {
    GEMM_PROLOG(384)
    f32x16 acc = gemm_tile_32x32(h1, wqkv, m0, n0, q, h5);
    #pragma unroll
    for (int r = 0; r < 16; ++r) {
        const int mr = m0 + (r & 3) + 8 * (r >> 2) + 4 * h5;
        const int b_ = mr >> 12, n = mr & 4095;
        const u16 val = f2b(acc[r]);
        if (o < 128) {
            qb[((size_t)(b_ * 4 + (o >> 5)) * NN + n) * HD + (o & 31)] = val;
        } else if (o < 256) {
            const int o2 = o - 128;
            kbuf[((size_t)(b_ * 4 + (o2 >> 5)) * NN + n) * HD + (o2 & 31)] = val;
        } else {
            vb[(size_t)mr * 128 + (o - 256)] = val;
        }
    }
}

// ---------- K3: V transpose -> VT[bh][d][n] ----------
__global__ __launch_bounds__(256) void k_vt(const u16* __restrict__ vb, u16* __restrict__ vtb) {
    __shared__ u16 lds[32][64];
    const int t = threadIdx.x;
    const int bh = blockIdx.y, b_ = bh >> 2, hh = bh & 3;
    const int n0 = blockIdx.x * 64;
    {
        const int i = t >> 2, d0 = (t & 3) * 8;
        u16x8 v = *(const u16x8*)(vb + (size_t)(b_ * NN + n0 + i) * 128 + hh * 32 + d0);
        #pragma unroll
        for (int j = 0; j < 8; ++j) lds[d0 + j][i] = v[j];
    }
    __syncthreads();
    {
        const int d = t >> 3, j0 = (t & 7) * 8;
        u16x8 v;
        #pragma unroll
        for (int u = 0; u < 8; ++u) v[u] = lds[d][j0 + u];
        *(u16x8*)(vtb + ((size_t)bh * 32 + d) * NN + n0 + j0) = v;
    }
}

// ---------- K4: MFMA flash attention (exp2 domain) ----------
// grid = (NB*NH, NN/32) -> bh = blockIdx.x so linear id % 8 pins each head to one XCD's L2.
// block = 256 (4 waves, split-K: wave w owns keys [w*1024, w*1024+1024))
__global__ __launch_bounds__(256, 4) void k_attn(
    const u16* __restrict__ qb, const u16* __restrict__ kbuf, const u16* __restrict__ vtb,
    u16* __restrict__ ctxb) {
    __shared__ float smx[4][32];
    __shared__ float slv[4][32];
    __shared__ float so[4][64][17];

    const int l = threadIdx.x & 63, w = threadIdx.x >> 6;
    const int q = l & 31, h5 = l >> 5;
    const int bh = blockIdx.x;
    const int qbase = blockIdx.y * 32;

    // Q B-fragments (scale*log2e pre-folded into weights)
    const u16* qp = qb + ((size_t)bh * NN + qbase + q) * HD + h5 * 8;
    const bf16x8 qf0 = *(const bf16x8*)qp;
    const bf16x8 qf1 = *(const bf16x8*)(qp + 16);

    const int kb0 = w * 1024;
    const u16* kp = kbuf + ((size_t)bh * NN + kb0 + q) * HD + h5 * 8;
    const u16* vp = vtb + ((size_t)bh * 32 + q) * NN + kb0 + h5 * 8;

    float m = -INFINITY, lacc = 0.f;
    f32x16 O = fzero16();

    // prefetched current tile
    bf16x8 kf0 = *(const bf16x8*)kp;
    bf16x8 kf1 = *(const bf16x8*)(kp + 16);
    bf16x8 vf0 = *(const bf16x8*)vp;
    bf16x8 vf1 = *(const bf16x8*)(vp + 16);

    for (int t = 0; t < 32; ++t) {
        // issue next tile's loads first (hide L2 latency under softmax VALU)
        const u16* kpn = kp + ((t < 31) ? 32 * HD : 0);
        const u16* vpn = vp + ((t < 31) ? 32 : 0);
        const bf16x8 nk0 = *(const bf16x8*)kpn;
        const bf16x8 nk1 = *(const bf16x8*)(kpn + 16);
        const bf16x8 nv0 = *(const bf16x8*)vpn;
        const bf16x8 nv1 = *(const bf16x8*)(vpn + 16);

        // S^T[key][q] = K_tile . Q^T  (two d-halves); values are log2-domain
        f32x16 s = fzero16();
        s = __builtin_amdgcn_mfma_f32_32x32x16_bf16(kf0, qf0, s, 0, 0, 0);
        s = __builtin_amdgcn_mfma_f32_32x32x16_bf16(kf1, qf1, s, 0, 0, 0);

        // tree max over own 16, then partner half via permlane swap
        float t0 = fmaxf(fmaxf(fmaxf(s[0], s[1]), fmaxf(s[2], s[3])),
                         fmaxf(fmaxf(s[4], s[5]), fmaxf(s[6], s[7])));
        float t1 = fmaxf(fmaxf(fmaxf(s[8], s[9]), fmaxf(s[10], s[11])),
                         fmaxf(fmaxf(s[12], s[13]), fmaxf(s[14], s[15])));
        float tm = fmaxf(t0, t1);
        tm = fmaxf(tm, xswap(tm, h5));

        // defer-max rescale (P bounded by 2^8)
        if (__any(tm > m + 8.0f)) {
            const float mn = fmaxf(m, tm);
            const float f = __builtin_amdgcn_exp2f(m - mn);
            lacc *= f;
            #pragma unroll
            for (int r = 0; r < 16; ++r) {
                const float fr = __shfl(f, (r & 3) + 8 * (r >> 2) + 4 * h5);
                O[r] *= fr;
            }
            m = mn;
        }

        float p[16];
        float ls = 0.f;
        #pragma unroll
        for (int r = 0; r < 16; ++r) { p[r] = __builtin_amdgcn_exp2f(s[r] - m); ls += p[r]; }
        ls += xswap(ls, h5);
        lacc += ls;

        // pack P to bf16 pairs; half-exchange via permlane32_swap (branchless)
        unsigned pk[8];
        #pragma unroll
        for (int i = 0; i < 8; ++i) pk[i] = pack_bf16(p[2 * i], p[2 * i + 1]);
        U32x4 a0, a1;
        {
            unsigned x0 = pk[0], x2 = pk[2]; plswap(x0, x2);
            unsigned x1 = pk[1], x3 = pk[3]; plswap(x1, x3);
            a0.u[0] = x0; a0.u[1] = x1; a0.u[2] = x2; a0.u[3] = x3;
            unsigned y0 = pk[4], y2 = pk[6]; plswap(y0, y2);
            unsigned y1 = pk[5], y3 = pk[7]; plswap(y1, y3);
            a1.u[0] = y0; a1.u[1] = y1; a1.u[2] = y2; a1.u[3] = y3;
        }
        O = __builtin_amdgcn_mfma_f32_32x32x16_bf16(a0.v, vf0, O, 0, 0, 0);
        O = __builtin_amdgcn_mfma_f32_32x32x16_bf16(a1.v, vf1, O, 0, 0, 0);

        kf0 = nk0; kf1 = nk1; vf0 = nv0; vf1 = nv1;
        kp = kpn; vp = vpn;
    }

    // ---- split-K merge across the 4 waves ----
    if (l < 32) smx[w][l] = m;
    __syncthreads();
    const float M = fmaxf(fmaxf(smx[0][q], smx[1][q]), fmaxf(smx[2][q], smx[3][q]));
    const float g = __builtin_amdgcn_exp2f(m - M);
    if (l < 32) slv[w][l] = lacc * g;
    #pragma unroll
    for (int r = 0; r < 16; ++r) {
        const float gr = __shfl(g, (r & 3) + 8 * (r >> 2) + 4 * h5);
        so[w][l][r] = O[r] * gr;
    }
    __syncthreads();

    const float Lq = slv[0][q] + slv[1][q] + slv[2][q] + slv[3][q];
    const float linv = 1.0f / Lq;
    const int b_ = bh >> 2, h_ = bh & 3;
    #pragma unroll
    for (int i = 0; i < 4; ++i) {
        const int r = 4 * w + i;
        const float os = so[0][l][r] + so[1][l][r] + so[2][l][r] + so[3][l][r];
        const int qr = (r & 3) + 8 * (r >> 2) + 4 * h5;
        const float fr = __shfl(linv, qr);
        ctxb[((size_t)(b_ * NN + qbase + qr)) * NC + h_ * 32 + q] = f2b(os * fr);
    }
}

// ---------- K5: fused proj GEMM + bias + residual + LN2 ----------
// grid = 256 blocks; block = 32 rows x 128 cols (4 waves, one 32x32 tile each)
__global__ __launch_bounds__(256) void k_proj_ln(
    const u16* __restrict__ ctxb, const u16* __restrict__ wproj,
    const float* __restrict__ pbias, const float* __restrict__ x,
    const float* __restrict__ lnw, const float* __restrict__ lnb,
    float* __restrict__ x2, u16* __restrict__ h2) {
    __shared__ float sx[32][129];
    const int l = threadIdx.x & 63, wid = threadIdx.x >> 6;
    const int q = l & 31, h5 = l >> 5;
    const int m0 = blockIdx.x * 32;
    const int n0 = wid * 32;
    const int o = n0 + q;

    f32x16 acc = gemm_tile_32x32(ctxb, wproj, m0, n0, q, h5);
    const float bo = pbias[o];
    #pragma unroll
    for (int r = 0; r < 16; ++r) {
        const int rr = (r & 3) + 8 * (r >> 2) + 4 * h5;
        const int mr = m0 + rr;
        const float xv = acc[r] + bo + x[(size_t)mr * NC + o];
        x2[(size_t)mr * NC + o] = xv;
        sx[rr][o] = xv;
    }
    __syncthreads();

    // LN phase: 8 threads per row, 16 cols each
    const int t = threadIdx.x;
    const int row = t >> 3, cs = (t & 7) * 16;
    float vals[16];
    float sum = 0.f, ss = 0.f;
    #pragma unroll
    for (int i = 0; i < 16; ++i) {
        const float v = sx[row][cs + i];
        vals[i] = v; sum += v; ss += v * v;
    }
    #pragma unroll
    for (int off = 1; off < 8; off <<= 1) {
        sum += __shfl_xor(sum, off);
        ss  += __shfl_xor(ss, off);
    }
    const float mean = sum * (1.0f / NC);
    const float var  = ss * (1.0f / NC) - mean * mean;
    const float rstd = rsqrtf(var + EPS);
    const size_t base = (size_t)(m0 + row) * NC + cs;
    #pragma unroll
    for (int i = 0; i < 16; i += 2) {
        const float h0 = (vals[i]     - mean) * rstd * lnw[cs + i]     + lnb[cs + i];
        const float h1 = (vals[i + 1] - mean) * rstd * lnw[cs + i + 1] + lnb[cs + i + 1];
        *(unsigned*)(h2 + base + i) = pack_bf16(h0, h1);
    }
}

// ---------- K6: conv1 GEMM (N=256) + bias -> x1 (f32) ----------
__global__ __launch_bounds__(256) void k_gemm_c1(
    const u16* __restrict__ h2, const u16* __restrict__ wc1,
    const float* __restrict__ bias, float* __restrict__ x1) {
    GEMM_PROLOG(256)
    f32x16 acc = gemm_tile_32x32(h2, wc1, m0, n0, q, h5);
    const float bo = bias[o];
    #pragma unroll
    for (int r = 0; r < 16; ++r) {
        const int mr = m0 + (r & 3) + 8 * (r >> 2) + 4 * h5;
        x1[(size_t)mr * 256 + o] = acc[r] + bo;
    }
}

// ---------- K7: dw3x3 + dw5x5 + SimpleGate (transposed weights) ----------
__global__ __launch_bounds__(128) void k_dwgate(
    const float* __restrict__ x1, const float* __restrict__ wt33, const float* __restrict__ wt55,
    const float* __restrict__ b33, const float* __restrict__ b55, u16* __restrict__ gatedb) {
    const int pb = blockIdx.x, c = threadIdx.x;
    const int b_ = pb >> 12, p = pb & 4095;
    const int py = p >> 6, px = p & 63;
    const float* base = x1 + (size_t)b_ * NN * C2;

    float a5 = 0.f, g5 = 0.f, a3 = 0.f, g3 = 0.f, ca = 0.f, cg = 0.f;
    #pragma unroll
    for (int dy = -2; dy <= 2; ++dy) {
        const int yy = py + dy;
        #pragma unroll
        for (int dx = -2; dx <= 2; ++dx) {
            const int xx = px + dx;
            const bool in = (yy >= 0) && (yy < HW) && (xx >= 0) && (xx < HW);
            const size_t off = (size_t)(yy * HW + xx) * C2;
            const float xa = in ? base[off + c] : 0.f;
            const float xg = in ? base[off + 128 + c] : 0.f;
            const int k5 = (dy + 2) * 5 + (dx + 2);
            a5 += xa * wt55[k5 * 256 + c];
            g5 += xg * wt55[k5 * 256 + 128 + c];
            if (dy >= -1 && dy <= 1 && dx >= -1 && dx <= 1) {
                const int k3 = (dy + 1) * 3 + (dx + 1);
                a3 += xa * wt33[k3 * 256 + c];
                g3 += xg * wt33[k3 * 256 + 128 + c];
            }
            if (dy == 0 && dx == 0) { ca = xa; cg = xg; }
        }
    }
    const float sa = ca + a3 + b33[c] + a5 + b55[c];
    const float sg = cg + g3 + b33[128 + c] + g5 + b55[128 + c];
    gatedb[(size_t)pb * 128 + c] = f2b(sa * sg);
}

// ---------- K8: conv4 GEMM + bias + residual -> out (f32) ----------
__global__ __launch_bounds__(256) void k_gemm_c4(
    const u16* __restrict__ gatedb, const u16* __restrict__ wc4,
    const float* __restrict__ bias, const float* __restrict__ x2, float* __restrict__ out) {
    GEMM_PROLOG(128)
    f32x16 acc = gemm_tile_32x32(gatedb, wc4, m0, n0, q, h5);
    const float bo = bias[o];
    #pragma unroll
    for (int r = 0; r < 16; ++r) {
        const int mr = m0 + (r & 3) + 8 * (r >> 2) + 4 * h5;
        out[(size_t)mr * 128 + o] = acc[r] + bo + x2[(size_t)mr * 128 + o];
    }
}

// ---------- launcher ----------
extern "C" void kernel_launch(void* const* d_in, const int* in_sizes, int n_in,
                              void* d_out, int out_size, void* d_ws, size_t ws_size,
                              hipStream_t stream) {
    const float* x      = (const float*)d_in[0];
    const float* ln1_w  = (const float*)d_in[3];
    const float* ln1_b  = (const float*)d_in[4];
    const float* q_w    = (const float*)d_in[5];
    const float* kv_w   = (const float*)d_in[6];
    const float* proj_w = (const float*)d_in[7];
    const float* proj_b = (const float*)d_in[8];
    const float* ln2_w  = (const float*)d_in[9];
    const float* ln2_b  = (const float*)d_in[10];
    const float* c1_w   = (const float*)d_in[11];
    const float* c1_b   = (const float*)d_in[12];
    const float* c33_w  = (const float*)d_in[13];
    const float* c33_b  = (const float*)d_in[14];
    const float* c55_w  = (const float*)d_in[15];
    const float* c55_b  = (const float*)d_in[16];
    const float* c4_w   = (const float*)d_in[17];
    const float* c4_b   = (const float*)d_in[18];

    char* p = (char*)d_ws;
    u16*   wqkv  = (u16*)p;   p += 384 * 128 * 2;
    u16*   wproj = (u16*)p;   p += 128 * 128 * 2;
    u16*   wc1   = (u16*)p;   p += 256 * 128 * 2;
    u16*   wc4   = (u16*)p;   p += 128 * 128 * 2;
    float* wt33  = (float*)p; p += 9 * 256 * 4;
    float* wt55  = (float*)p; p += 25 * 256 * 4;
    u16*   h1    = (u16*)p;   p += (size_t)8192 * 128 * 2;
    u16*   qb    = (u16*)p;   p += (size_t)8 * 4096 * 32 * 2;
    u16*   kb    = (u16*)p;   p += (size_t)8 * 4096 * 32 * 2;
    u16*   vb    = (u16*)p;   p += (size_t)8192 * 128 * 2;
    u16*   vtb   = (u16*)p;   p += (size_t)8 * 32 * 4096 * 2;
    u16*   ctxb  = (u16*)p;   p += (size_t)8192 * 128 * 2;
    float* x2    = (float*)p; p += (size_t)8192 * 128 * 4;
    u16*   h2    = (u16*)p;   p += (size_t)8192 * 128 * 2;
    float* x1    = (float*)p; p += (size_t)8192 * 256 * 4;
    u16*   gatedb= (u16*)p;   p += (size_t)8192 * 128 * 2;
    float* out   = (float*)d_out;

    k_prep<<<64, 256, 0, stream>>>(q_w, kv_w, proj_w, c1_w, c4_w, c33_w, c55_w,
                                   wqkv, wproj, wc1, wc4, wt33, wt55);
    k_ln<<<2048, 256, 0, stream>>>(x, ln1_w, ln1_b, h1);
    k_gemm_qkv<<<dim3(128, 6), 256, 0, stream>>>(h1, wqkv, qb, kb, vb);
    k_vt<<<dim3(64, 8), 256, 0, stream>>>(vb, vtb);
    k_attn<<<dim3(NB * NH, NN / 32), 256, 0, stream>>>(qb, kb, vtb, ctxb);
    k_proj_ln<<<256, 256, 0, stream>>>(ctxb, wproj, proj_b, x, ln2_w, ln2_b, x2, h2);
    k_gemm_c1<<<dim3(128, 4), 256, 0, stream>>>(h2, wc1, c1_b, x1);
    k_dwgate<<<NB * NN, 128, 0, stream>>>(x1, wt33, wt55, c33_b, c55_b, gatedb);
    k_gemm_c4<<<dim3(128, 2), 256, 0, stream>>>(gatedb, wc4, c4_b, x2, out);
}